// Round 8
// baseline (363.425 us; speedup 1.0000x reference)
//
#include <hip/hip_runtime.h>

typedef unsigned short u16;
typedef __bf16 bf16x8 __attribute__((ext_vector_type(8)));
typedef float f32x4 __attribute__((ext_vector_type(4)));

__device__ __forceinline__ u16 f2bf(float f) {
  union { float f; unsigned u; } v; v.f = f;
  unsigned r = v.u + 0x7FFFu + ((v.u >> 16) & 1u);
  return (u16)(r >> 16);
}

__device__ __forceinline__ void gload16(const void* g, void* l) {
  __builtin_amdgcn_global_load_lds(
      (const __attribute__((address_space(1))) unsigned int*)g,
      (__attribute__((address_space(3))) unsigned int*)l, 16, 0, 0);
}

// ---------------- fp32 -> bf16 convert (vectorized, grid-stride) -------------
__global__ __launch_bounds__(256) void cvt_bf16(const float* __restrict__ in,
                                                u16* __restrict__ out, long n) {
  long i = ((long)blockIdx.x * 256 + threadIdx.x) * 8;
  const long stride = (long)gridDim.x * 2048;
  for (; i < n; i += stride) {
    float4 a = *(const float4*)(in + i);
    float4 b = *(const float4*)(in + i + 4);
    uint4 o;
    o.x = (unsigned)f2bf(a.x) | ((unsigned)f2bf(a.y) << 16);
    o.y = (unsigned)f2bf(a.z) | ((unsigned)f2bf(a.w) << 16);
    o.z = (unsigned)f2bf(b.x) | ((unsigned)f2bf(b.y) << 16);
    o.w = (unsigned)f2bf(b.z) | ((unsigned)f2bf(b.w) << 16);
    *(uint4*)(out + i) = o;
  }
}

// ---------------- NT GEMM, m201-cadence 4-phase pipeline ---------------------
// C[M,N] = A[M,K]*B[N,K]^T. BK=64 (rows 128B), LDS [row][64k] bf16 with
// byte-swizzle ^((row&7)<<4) on BOTH sides (k-slice offset INSIDE the XOR).
// 8 waves as WMxWN. Per K-tile: 4 phases (k-half s=p>>1, m-half mh=p&1):
//   {issue phase ds_reads; issue ~2 next-tile gloads; s_barrier;
//    lgkmcnt(0)+sched_barrier; setprio(1) MFMA cluster setprio(0)}
// One vmcnt(0)+s_barrier per tile (loads are a full tile old -> free drain).
// The per-phase barrier cadence forces cross-wave anti-phase so the CU's LDS
// pipe (the co-limiting resource) overlaps the MFMA pipe.
template <int BM, int BN, int WM, typename OUT>
__global__ __launch_bounds__(512, 2) void gemmP(const u16* __restrict__ A,
                                                const u16* __restrict__ B,
                                                OUT* __restrict__ C,
                                                int M, int N, int K) {
  constexpr int WN = 8 / WM;
  constexpr int MREP = BM / WM / 16;   // == 4 (phase split needs it)
  constexpr int NREP = BN / WN / 16;
  constexpr int AI = BM / 64;          // A stage instrs
  constexpr int BI = BN / 64;          // B stage instrs
  static_assert(MREP == 4, "phase split assumes MREP==4");
  __shared__ __align__(16) u16 sA[2][BM * 64];
  __shared__ __align__(16) u16 sB[2][BN * 64];

  const int tid = threadIdx.x;
  const int w = tid >> 6, ln = tid & 63;
  const int lr = ln & 15, lg = ln >> 4;
  const int wr = w / WN, wc = w % WN;

  const int nN = N / BN;
  const int bm = ((int)blockIdx.x / nN) * BM;
  const int bn = ((int)blockIdx.x % nN) * BN;

  // staging source (pre-swizzled column; involution of the read swizzle)
  const int srow = tid >> 3;
  const int scol = (((tid & 7) * 16) ^ ((srow & 7) << 4)) >> 1;  // u16 units
  const u16* pA = A + (size_t)(bm + srow) * K + scol;
  const u16* pB = B + (size_t)(bn + srow) * K + scol;

  const int mask = (lr & 7) << 4;
  const int pAr = (wr * (BM / WM) + lr) * 128;
  const int pBr = (wc * (BN / WN) + lr) * 128;

  f32x4 acc[MREP][NREP] = {};
  const int nk = K >> 6;

  auto stageAll = [&](int buf, int t) {
    const int k0 = t << 6;
#pragma unroll
    for (int i = 0; i < AI; ++i)
      gload16(pA + (size_t)i * 64 * K + k0, (char*)sA[buf] + i * 8192 + tid * 16);
#pragma unroll
    for (int i = 0; i < BI; ++i)
      gload16(pB + (size_t)i * 64 * K + k0, (char*)sB[buf] + i * 8192 + tid * 16);
  };
  auto stageChunk = [&](int buf, int t, int p) {
    const int k0 = t << 6;
#pragma unroll
    for (int i = 0; i < AI; ++i)
      if ((i & 3) == p)
        gload16(pA + (size_t)i * 64 * K + k0, (char*)sA[buf] + i * 8192 + tid * 16);
#pragma unroll
    for (int i = 0; i < BI; ++i)
      if (((AI + i) & 3) == p)
        gload16(pB + (size_t)i * 64 * K + k0, (char*)sB[buf] + i * 8192 + tid * 16);
  };

  stageAll(0, 0);

#pragma unroll 1
  for (int t = 0; t < nk; ++t) {
    const int buf = t & 1;
    const char* lA = (const char*)sA[buf];
    const char* lB = (const char*)sB[buf];

    asm volatile("s_waitcnt vmcnt(0)" ::: "memory");
    __builtin_amdgcn_s_barrier();
    __builtin_amdgcn_sched_barrier(0);

    bf16x8 bfr[NREP];
#pragma unroll
    for (int p = 0; p < 4; ++p) {
      const int s = p >> 1, mh = p & 1;
      // phase ds_reads (B-frags re-read at each k-half; A 2 frags/phase)
      if (mh == 0) {
#pragma unroll
        for (int nf = 0; nf < NREP; ++nf)
          bfr[nf] = *(const bf16x8*)(lB + pBr + nf * 2048 +
                                     ((lg * 16 + s * 64) ^ mask));
      }
      bf16x8 af0 = *(const bf16x8*)(lA + pAr + (2 * mh) * 2048 +
                                    ((lg * 16 + s * 64) ^ mask));
      bf16x8 af1 = *(const bf16x8*)(lA + pAr + (2 * mh + 1) * 2048 +
                                    ((lg * 16 + s * 64) ^ mask));
      if (t + 1 < nk) stageChunk(buf ^ 1, t + 1, p);

      __builtin_amdgcn_s_barrier();
      asm volatile("s_waitcnt lgkmcnt(0)" ::: "memory");
      __builtin_amdgcn_sched_barrier(0);   // rule #18
      __builtin_amdgcn_s_setprio(1);
#pragma unroll
      for (int nf = 0; nf < NREP; ++nf) {
        acc[2 * mh][nf] = __builtin_amdgcn_mfma_f32_16x16x32_bf16(
            af0, bfr[nf], acc[2 * mh][nf], 0, 0, 0);
        acc[2 * mh + 1][nf] = __builtin_amdgcn_mfma_f32_16x16x32_bf16(
            af1, bfr[nf], acc[2 * mh + 1][nf], 0, 0, 0);
      }
      __builtin_amdgcn_s_setprio(0);
    }
  }

#pragma unroll
  for (int m = 0; m < MREP; ++m)
#pragma unroll
    for (int nf = 0; nf < NREP; ++nf)
#pragma unroll
      for (int r = 0; r < 4; ++r) {
        const int row = bm + wr * (BM / WM) + m * 16 + lg * 4 + r;
        const int col = bn + wc * (BN / WN) + nf * 16 + lr;
        const float v = acc[m][nf][r];
        if constexpr (sizeof(OUT) == 2)
          C[(size_t)row * N + col] = (OUT)f2bf(v);
        else
          C[(size_t)row * N + col] = v;
      }
}

// ---------------- V transpose: vT[hk][d][t] = qkv[t][5120 + hk*128 + d] ------
__global__ __launch_bounds__(256) void vtrans(const u16* __restrict__ qkv,
                                              u16* __restrict__ vT) {
  __shared__ u16 tile[128][65];
  const int hk = blockIdx.y;
  const int tb = blockIdx.x * 64;
  const int tid = threadIdx.x;
#pragma unroll
  for (int p = 0; p < 4; ++p) {
    const int tr = p * 16 + (tid >> 4);
    const int d0 = (tid & 15) * 8;
    const uint4 x = *(const uint4*)(qkv + (size_t)(tb + tr) * 6144 + 5120 + hk * 128 + d0);
    const u16* xv = (const u16*)&x;
#pragma unroll
    for (int j = 0; j < 8; ++j) tile[d0 + j][tr] = xv[j];
  }
  __syncthreads();
#pragma unroll
  for (int p = 0; p < 4; ++p) {
    const int d = p * 32 + (tid >> 3);
    const int t0 = (tid & 7) * 8;
    u16 v[8];
#pragma unroll
    for (int j = 0; j < 8; ++j) v[j] = tile[d][t0 + j];
    uint4 o;
    unsigned* ov = (unsigned*)&o;
#pragma unroll
    for (int j = 0; j < 4; ++j)
      ov[j] = (unsigned)v[2 * j] | ((unsigned)v[2 * j + 1] << 16);
    *(uint4*)(vT + (size_t)hk * 128 * 2048 + (size_t)d * 2048 + tb + t0) = o;
  }
}

// ---------------- flash attention (causal GQA), paired q-tiles + dbuf --------
__global__ __launch_bounds__(256) void attn(const u16* __restrict__ qkv,
                                            const u16* __restrict__ vT,
                                            u16* __restrict__ ctx) {
  __shared__ __align__(16) u16 sK[2][64 * 128];
  __shared__ __align__(16) u16 sV[2][128 * 64];
  __shared__ __align__(16) u16 sP[4 * 16 * 64];
  const int tid = threadIdx.x, w = tid >> 6, ln = tid & 63;
  const int lr = ln & 15, lg = ln >> 4;
  const int h = blockIdx.y, hk = h >> 2;
  const int pi = blockIdx.x;

  const float scale = 0.08838834764831845f;  // 1/sqrt(128)
  const float LOG2E = 1.4426950408889634f;
  char* const pw = (char*)sP + w * 2048;

  auto stage = [&](int buf, int kt) {
    const int kvbase = kt * 64;
#pragma unroll
    for (int i = 0; i < 4; ++i) {
      const int off = i * 4096 + tid * 16;
      {
        const int row = off >> 8, cbp = off & 255;
        const int cb = cbp ^ ((row & 7) << 4);
        gload16(qkv + (size_t)(kvbase + row) * 6144 + 4096 + hk * 128 + (cb >> 1),
                (char*)sK + buf * 16384 + off);
      }
      {
        const int row = off >> 7, cbp = off & 127;
        const int cb = cbp ^ ((row & 7) << 4);
        gload16(vT + (size_t)hk * 262144 + (size_t)row * 2048 + kvbase + (cb >> 1),
                (char*)sV + buf * 16384 + off);
      }
    }
  };

#pragma unroll 1
  for (int ph = 0; ph < 2; ++ph) {
    const int qt = ph ? (31 - pi) : pi;
    const int qbase = qt * 64;
    const int nkt = qt + 1;

    bf16x8 qf[4];
    {
      const u16* qrow = qkv + (size_t)(qbase + w * 16 + lr) * 6144 + h * 128 + lg * 8;
#pragma unroll
      for (int kk = 0; kk < 4; ++kk) qf[kk] = *(const bf16x8*)(qrow + kk * 32);
    }

    f32x4 acc_o[8] = {};
    float m_r[4] = {-INFINITY, -INFINITY, -INFINITY, -INFINITY};
    float l_r[4] = {0.f, 0.f, 0.f, 0.f};

    stage(0, 0);

#pragma unroll 1
    for (int kt = 0; kt < nkt; ++kt) {
      const int buf = kt & 1;
      const int kvbase = kt * 64;
      __syncthreads();
      if (kt + 1 < nkt) stage(buf ^ 1, kt + 1);

      char* const kbase = (char*)sK + buf * 16384;
      char* const vbase = (char*)sV + buf * 16384;

      f32x4 sacc[4] = {};
#pragma unroll
      for (int kk = 0; kk < 4; ++kk) {
#pragma unroll
        for (int nf = 0; nf < 4; ++nf) {
          const int row = nf * 16 + lr;
          const int byt = row * 256 + ((kk * 64 + lg * 16) ^ ((row & 7) << 4));
          const bf16x8 kf = *(const bf16x8*)(kbase + byt);
          sacc[nf] = __builtin_amdgcn_mfma_f32_16x16x32_bf16(qf[kk], kf, sacc[nf], 0, 0, 0);
        }
      }

      const bool diag = (kt == qt);
      float p[4][4];
#pragma unroll
      for (int r = 0; r < 4; ++r) {
        const int qrow = qbase + w * 16 + lg * 4 + r;
        float mx = -INFINITY;
#pragma unroll
        for (int nf = 0; nf < 4; ++nf) {
          float v = sacc[nf][r] * scale;
          if (diag && (kvbase + nf * 16 + lr > qrow)) v = -INFINITY;
          p[nf][r] = v;
          mx = fmaxf(mx, v);
        }
        mx = fmaxf(mx, __shfl_xor(mx, 1));
        mx = fmaxf(mx, __shfl_xor(mx, 2));
        mx = fmaxf(mx, __shfl_xor(mx, 4));
        mx = fmaxf(mx, __shfl_xor(mx, 8));
        const float mt = fmaxf(m_r[r], mx);
        const float alpha = exp2f((m_r[r] - mt) * LOG2E);
        m_r[r] = mt;
        float rs = 0.f;
#pragma unroll
        for (int nf = 0; nf < 4; ++nf) {
          const float e = exp2f((p[nf][r] - mt) * LOG2E);
          p[nf][r] = e;
          rs += e;
        }
        rs += __shfl_xor(rs, 1);
        rs += __shfl_xor(rs, 2);
        rs += __shfl_xor(rs, 4);
        rs += __shfl_xor(rs, 8);
        l_r[r] = l_r[r] * alpha + rs;
#pragma unroll
        for (int o = 0; o < 8; ++o) acc_o[o][r] = acc_o[o][r] * alpha;
      }

#pragma unroll
      for (int r = 0; r < 4; ++r) {
        const int row = lg * 4 + r;
#pragma unroll
        for (int nf = 0; nf < 4; ++nf) {
          const int col = nf * 16 + lr;
          const int byt = row * 128 + ((2 * col) ^ ((row & 7) << 4));
          *(u16*)(pw + byt) = f2bf(p[nf][r]);
        }
      }

#pragma unroll
      for (int kk2 = 0; kk2 < 2; ++kk2) {
        const int pbyt = lr * 128 + ((kk2 * 64 + lg * 16) ^ ((lr & 7) << 4));
        const bf16x8 pf = *(const bf16x8*)(pw + pbyt);
#pragma unroll
        for (int o = 0; o < 8; ++o) {
          const int vrow = o * 16 + lr;
          const int vbyt = vrow * 128 + ((kk2 * 64 + lg * 16) ^ ((vrow & 7) << 4));
          const bf16x8 vf = *(const bf16x8*)(vbase + vbyt);
          acc_o[o] = __builtin_amdgcn_mfma_f32_16x16x32_bf16(pf, vf, acc_o[o], 0, 0, 0);
        }
      }
    }

#pragma unroll
    for (int r = 0; r < 4; ++r) {
      const float inv = 1.f / l_r[r];
      const int t = qbase + w * 16 + lg * 4 + r;
#pragma unroll
      for (int o = 0; o < 8; ++o)
        ctx[(size_t)t * 4096 + h * 128 + o * 16 + lr] = f2bf(acc_o[o][r] * inv);
    }
    __syncthreads();
  }
}

// ---------------- launch -----------------------------------------------------
extern "C" void kernel_launch(void* const* d_in, const int* in_sizes, int n_in,
                              void* d_out, int out_size, void* d_ws, size_t ws_size,
                              hipStream_t stream) {
  (void)in_sizes; (void)n_in; (void)out_size; (void)ws_size;
  const float* hidden = (const float*)d_in[1];
  const float* w_qkv = (const float*)d_in[2];
  const float* w_o = (const float*)d_in[3];
  float* out = (float*)d_out;
  char* ws = (char*)d_ws;

  u16* xb    = (u16*)(ws + 0);                   // 2048*4096   bf16  (16 MB)
  u16* wqkvb = (u16*)(ws + 16777216);            // 6144*4096   bf16  (48 MB)
  u16* wob   = (u16*)(ws + 67108864);            // 4096*4096   bf16  (32 MB)
  u16* qkvb  = (u16*)(ws + 100663296);           // 2048*6144   bf16  (24 MB)
  u16* vTb   = (u16*)(ws + 125829120);           // 8*128*2048  bf16  (4 MB)
  u16* ctxb  = (u16*)(ws + 130023424);           // 2048*4096   bf16  (16 MB)

  cvt_bf16<<<4096, 256, 0, stream>>>(hidden, xb, (long)2048 * 4096);
  cvt_bf16<<<8192, 256, 0, stream>>>(w_qkv, wqkvb, (long)6144 * 4096);
  cvt_bf16<<<8192, 256, 0, stream>>>(w_o, wob, (long)4096 * 4096);
  // QKV: 256x192 tiles, 4Mx2N waves -> 8x32 = 256 blocks (1/CU, 100% fill)
  gemmP<256, 192, 4, u16><<<256, 512, 0, stream>>>(xb, wqkvb, qkvb, 2048, 6144, 4096);
  vtrans<<<dim3(32, 8), 256, 0, stream>>>(qkvb, vTb);
  attn<<<dim3(16, 32), 256, 0, stream>>>(qkvb, vTb, ctxb);
  // O-proj: 128x256 tiles, 2Mx4N waves -> 16x16 = 256 blocks
  gemmP<128, 256, 2, float><<<256, 512, 0, stream>>>(ctxb, wob, out, 2048, 4096, 4096);
}

// Round 9
// 334.585 us; speedup vs baseline: 1.0862x; 1.0862x over previous
//
#include <hip/hip_runtime.h>

typedef unsigned short u16;
typedef __bf16 bf16x8 __attribute__((ext_vector_type(8)));
typedef float f32x4 __attribute__((ext_vector_type(4)));

__device__ __forceinline__ u16 f2bf(float f) {
  union { float f; unsigned u; } v; v.f = f;
  unsigned r = v.u + 0x7FFFu + ((v.u >> 16) & 1u);
  return (u16)(r >> 16);
}

__device__ __forceinline__ void gload16(const void* g, void* l) {
  __builtin_amdgcn_global_load_lds(
      (const __attribute__((address_space(1))) unsigned int*)g,
      (__attribute__((address_space(3))) unsigned int*)l, 16, 0, 0);
}

// ---------------- fp32 -> bf16 convert (vectorized, grid-stride) -------------
__global__ __launch_bounds__(256) void cvt_bf16(const float* __restrict__ in,
                                                u16* __restrict__ out, long n) {
  long i = ((long)blockIdx.x * 256 + threadIdx.x) * 8;
  const long stride = (long)gridDim.x * 2048;
  for (; i < n; i += stride) {
    float4 a = *(const float4*)(in + i);
    float4 b = *(const float4*)(in + i + 4);
    uint4 o;
    o.x = (unsigned)f2bf(a.x) | ((unsigned)f2bf(a.y) << 16);
    o.y = (unsigned)f2bf(a.z) | ((unsigned)f2bf(a.w) << 16);
    o.z = (unsigned)f2bf(b.x) | ((unsigned)f2bf(b.y) << 16);
    o.w = (unsigned)f2bf(b.z) | ((unsigned)f2bf(b.w) << 16);
    *(uint4*)(out + i) = o;
  }
}

// ---------------- NT GEMM, phase-major A layout + counted vmcnt (T3+T4) ------
// C[M,N] = A[M,K]*B[N,K]^T. BK=64, 8 waves (2Mx4N), wave tile (BM/2)x(BN/4).
// A's LDS rows are PHASE-MAJOR permuted: stage-block i == phase-i rows for
// both wave halves (row' = q*2QS + wr*QS + j*16 + lr; staging side collapses
// to global row = gA0 + i*32). B identity, read whole into regs at phase 0.
// Stage order [B.., A0..A3] issued {2,2,1,AI/2}/phase; counted waits:
// vmcnt(AI/2) pre-phase0, vmcnt(4) pre-phase2 (vmcnt(0) last tile) -> every
// confirmed load is >=2 phases old; no full drain in the main loop.
// Byte-swizzle ^((row&7)<<4) both sides, k-slice offset INSIDE the XOR.
template <int BM, int BN, typename OUT>
__global__ __launch_bounds__(512, 2) void gemmQ(const u16* __restrict__ A,
                                                const u16* __restrict__ B,
                                                OUT* __restrict__ C,
                                                int M, int N, int K) {
  constexpr int MREP = BM / 32;        // per-wave M frags (8 / 4)
  constexpr int NREP = BN / 64;        // per-wave N frags (3 / 4)
  constexpr int MQ = MREP / 4;         // M frags per phase (2 / 1)
  constexpr int QS = MQ * 16;          // phase row-quarter size (32 / 16)
  constexpr int AI = BM / 64;          // A stage gloads (4 / 2)
  constexpr int BI = BN / 64;          // B stage gloads (3 / 4)
  constexpr int TE = AI + BI;          // total stage entries (7 / 6)
  static_assert(MREP % 4 == 0, "need 4 m-quarters");
  __shared__ __align__(16) u16 sA[2][BM * 64];
  __shared__ __align__(16) u16 sB[2][BN * 64];

  const int tid = threadIdx.x;
  const int w = tid >> 6, ln = tid & 63;
  const int lr = ln & 15, lg = ln >> 4;
  const int wr = w >> 2, wc = w & 3;

  const int nN = N / BN;
  const int bm = ((int)blockIdx.x / nN) * BM;
  const int bn = ((int)blockIdx.x % nN) * BN;

  // staging source (pre-swizzled column; involution of the read swizzle)
  const int s_r = tid >> 3;                                   // LDS row' % 64
  const int scol = (((tid & 7) * 16) ^ ((s_r & 7) << 4)) >> 1; // u16 units
  // inverse phase-major perm, collapsed: global A row = gA0 + i*32
  const int gA0 = ((s_r / QS) & 1) * (BM / 2) + (s_r / (2 * QS)) * QS +
                  (s_r & (QS - 1));
  const u16* pAb = A + (size_t)(bm + gA0) * K + scol;
  const u16* pBb = B + (size_t)(bn + s_r) * K + scol;

  const int mask = (lr & 7) << 4;
  const int pBr = (wc * (BN / 4) + lr) * 128;

  f32x4 acc[MREP][NREP] = {};
  const int nk = K >> 6;

  // stage entry j of a tile: j<BI -> B block j; else A phase-block (j-BI)
  auto stage1 = [&](int buf, int k0, int j) {
    if (j < BI)
      gload16(pBb + (size_t)j * 64 * K + k0, (char*)sB[buf] + j * 8192 + tid * 16);
    else {
      const int i = j - BI;
      gload16(pAb + (size_t)i * 32 * K + k0, (char*)sA[buf] + i * 8192 + tid * 16);
    }
  };

  // prologue: tile 0 fully, in list order
#pragma unroll
  for (int j = 0; j < TE; ++j) stage1(0, 0, j);

  constexpr int S[4] = {0, 2, 4, TE - AI / 2};
  constexpr int E[4] = {2, 4, TE - AI / 2, TE};

#pragma unroll 1
  for (int t = 0; t < nk; ++t) {
    const int buf = t & 1;
    const int k1 = (t + 1) << 6;
    const bool more = (t + 1 < nk);
    const char* lA = (const char*)sA[buf];
    const char* lB = (const char*)sB[buf];

    bf16x8 bfr[NREP][2];
#pragma unroll
    for (int q = 0; q < 4; ++q) {
      if (q == 0) {
        if constexpr (AI == 4) asm volatile("s_waitcnt vmcnt(2)" ::: "memory");
        else                   asm volatile("s_waitcnt vmcnt(1)" ::: "memory");
      } else if (q == 2) {
        if (more) asm volatile("s_waitcnt vmcnt(4)" ::: "memory");
        else      asm volatile("s_waitcnt vmcnt(0)" ::: "memory");
      }
      __builtin_amdgcn_s_barrier();
      __builtin_amdgcn_sched_barrier(0);

      if (q == 0) {  // B whole tile -> regs, held across all 4 phases
#pragma unroll
        for (int nf = 0; nf < NREP; ++nf)
#pragma unroll
          for (int s = 0; s < 2; ++s)
            bfr[nf][s] = *(const bf16x8*)(lB + pBr + nf * 2048 +
                                          ((lg * 16 + s * 64) ^ mask));
      }
      bf16x8 af[MQ][2];
#pragma unroll
      for (int j = 0; j < MQ; ++j)
#pragma unroll
        for (int s = 0; s < 2; ++s)
          af[j][s] = *(const bf16x8*)(
              lA + (q * 2 * QS + wr * QS + j * 16 + lr) * 128 +
              ((lg * 16 + s * 64) ^ mask));

      if (more) {
#pragma unroll
        for (int j = S[q]; j < E[q]; ++j) stage1(buf ^ 1, k1, j);
      }

      asm volatile("s_waitcnt lgkmcnt(0)" ::: "memory");
      __builtin_amdgcn_sched_barrier(0);   // rule #18
      __builtin_amdgcn_s_setprio(1);
#pragma unroll
      for (int s = 0; s < 2; ++s)
#pragma unroll
        for (int j = 0; j < MQ; ++j)
#pragma unroll
          for (int nf = 0; nf < NREP; ++nf)
            acc[q * MQ + j][nf] = __builtin_amdgcn_mfma_f32_16x16x32_bf16(
                af[j][s], bfr[nf][s], acc[q * MQ + j][nf], 0, 0, 0);
      __builtin_amdgcn_s_setprio(0);
    }
  }

#pragma unroll
  for (int m = 0; m < MREP; ++m)
#pragma unroll
    for (int nf = 0; nf < NREP; ++nf)
#pragma unroll
      for (int r = 0; r < 4; ++r) {
        const int row = bm + wr * (BM / 2) + m * 16 + lg * 4 + r;
        const int col = bn + wc * (BN / 4) + nf * 16 + lr;
        const float v = acc[m][nf][r];
        if constexpr (sizeof(OUT) == 2)
          C[(size_t)row * N + col] = (OUT)f2bf(v);
        else
          C[(size_t)row * N + col] = v;
      }
}

// ---------------- V transpose: vT[hk][d][t] = qkv[t][5120 + hk*128 + d] ------
__global__ __launch_bounds__(256) void vtrans(const u16* __restrict__ qkv,
                                              u16* __restrict__ vT) {
  __shared__ u16 tile[128][65];
  const int hk = blockIdx.y;
  const int tb = blockIdx.x * 64;
  const int tid = threadIdx.x;
#pragma unroll
  for (int p = 0; p < 4; ++p) {
    const int tr = p * 16 + (tid >> 4);
    const int d0 = (tid & 15) * 8;
    const uint4 x = *(const uint4*)(qkv + (size_t)(tb + tr) * 6144 + 5120 + hk * 128 + d0);
    const u16* xv = (const u16*)&x;
#pragma unroll
    for (int j = 0; j < 8; ++j) tile[d0 + j][tr] = xv[j];
  }
  __syncthreads();
#pragma unroll
  for (int p = 0; p < 4; ++p) {
    const int d = p * 32 + (tid >> 3);
    const int t0 = (tid & 7) * 8;
    u16 v[8];
#pragma unroll
    for (int j = 0; j < 8; ++j) v[j] = tile[d][t0 + j];
    uint4 o;
    unsigned* ov = (unsigned*)&o;
#pragma unroll
    for (int j = 0; j < 4; ++j)
      ov[j] = (unsigned)v[2 * j] | ((unsigned)v[2 * j + 1] << 16);
    *(uint4*)(vT + (size_t)hk * 128 * 2048 + (size_t)d * 2048 + tb + t0) = o;
  }
}

// ---------------- flash attention (causal GQA), paired q-tiles + dbuf --------
__global__ __launch_bounds__(256) void attn(const u16* __restrict__ qkv,
                                            const u16* __restrict__ vT,
                                            u16* __restrict__ ctx) {
  __shared__ __align__(16) u16 sK[2][64 * 128];
  __shared__ __align__(16) u16 sV[2][128 * 64];
  __shared__ __align__(16) u16 sP[4 * 16 * 64];
  const int tid = threadIdx.x, w = tid >> 6, ln = tid & 63;
  const int lr = ln & 15, lg = ln >> 4;
  const int h = blockIdx.y, hk = h >> 2;
  const int pi = blockIdx.x;

  const float scale = 0.08838834764831845f;  // 1/sqrt(128)
  const float LOG2E = 1.4426950408889634f;
  char* const pw = (char*)sP + w * 2048;

  auto stage = [&](int buf, int kt) {
    const int kvbase = kt * 64;
#pragma unroll
    for (int i = 0; i < 4; ++i) {
      const int off = i * 4096 + tid * 16;
      {
        const int row = off >> 8, cbp = off & 255;
        const int cb = cbp ^ ((row & 7) << 4);
        gload16(qkv + (size_t)(kvbase + row) * 6144 + 4096 + hk * 128 + (cb >> 1),
                (char*)sK + buf * 16384 + off);
      }
      {
        const int row = off >> 7, cbp = off & 127;
        const int cb = cbp ^ ((row & 7) << 4);
        gload16(vT + (size_t)hk * 262144 + (size_t)row * 2048 + kvbase + (cb >> 1),
                (char*)sV + buf * 16384 + off);
      }
    }
  };

#pragma unroll 1
  for (int ph = 0; ph < 2; ++ph) {
    const int qt = ph ? (31 - pi) : pi;
    const int qbase = qt * 64;
    const int nkt = qt + 1;

    bf16x8 qf[4];
    {
      const u16* qrow = qkv + (size_t)(qbase + w * 16 + lr) * 6144 + h * 128 + lg * 8;
#pragma unroll
      for (int kk = 0; kk < 4; ++kk) qf[kk] = *(const bf16x8*)(qrow + kk * 32);
    }

    f32x4 acc_o[8] = {};
    float m_r[4] = {-INFINITY, -INFINITY, -INFINITY, -INFINITY};
    float l_r[4] = {0.f, 0.f, 0.f, 0.f};

    stage(0, 0);

#pragma unroll 1
    for (int kt = 0; kt < nkt; ++kt) {
      const int buf = kt & 1;
      const int kvbase = kt * 64;
      __syncthreads();
      if (kt + 1 < nkt) stage(buf ^ 1, kt + 1);

      char* const kbase = (char*)sK + buf * 16384;
      char* const vbase = (char*)sV + buf * 16384;

      f32x4 sacc[4] = {};
#pragma unroll
      for (int kk = 0; kk < 4; ++kk) {
#pragma unroll
        for (int nf = 0; nf < 4; ++nf) {
          const int row = nf * 16 + lr;
          const int byt = row * 256 + ((kk * 64 + lg * 16) ^ ((row & 7) << 4));
          const bf16x8 kf = *(const bf16x8*)(kbase + byt);
          sacc[nf] = __builtin_amdgcn_mfma_f32_16x16x32_bf16(qf[kk], kf, sacc[nf], 0, 0, 0);
        }
      }

      const bool diag = (kt == qt);
      float p[4][4];
#pragma unroll
      for (int r = 0; r < 4; ++r) {
        const int qrow = qbase + w * 16 + lg * 4 + r;
        float mx = -INFINITY;
#pragma unroll
        for (int nf = 0; nf < 4; ++nf) {
          float v = sacc[nf][r] * scale;
          if (diag && (kvbase + nf * 16 + lr > qrow)) v = -INFINITY;
          p[nf][r] = v;
          mx = fmaxf(mx, v);
        }
        mx = fmaxf(mx, __shfl_xor(mx, 1));
        mx = fmaxf(mx, __shfl_xor(mx, 2));
        mx = fmaxf(mx, __shfl_xor(mx, 4));
        mx = fmaxf(mx, __shfl_xor(mx, 8));
        const float mt = fmaxf(m_r[r], mx);
        const float alpha = exp2f((m_r[r] - mt) * LOG2E);
        m_r[r] = mt;
        float rs = 0.f;
#pragma unroll
        for (int nf = 0; nf < 4; ++nf) {
          const float e = exp2f((p[nf][r] - mt) * LOG2E);
          p[nf][r] = e;
          rs += e;
        }
        rs += __shfl_xor(rs, 1);
        rs += __shfl_xor(rs, 2);
        rs += __shfl_xor(rs, 4);
        rs += __shfl_xor(rs, 8);
        l_r[r] = l_r[r] * alpha + rs;
#pragma unroll
        for (int o = 0; o < 8; ++o) acc_o[o][r] = acc_o[o][r] * alpha;
      }

#pragma unroll
      for (int r = 0; r < 4; ++r) {
        const int row = lg * 4 + r;
#pragma unroll
        for (int nf = 0; nf < 4; ++nf) {
          const int col = nf * 16 + lr;
          const int byt = row * 128 + ((2 * col) ^ ((row & 7) << 4));
          *(u16*)(pw + byt) = f2bf(p[nf][r]);
        }
      }

#pragma unroll
      for (int kk2 = 0; kk2 < 2; ++kk2) {
        const int pbyt = lr * 128 + ((kk2 * 64 + lg * 16) ^ ((lr & 7) << 4));
        const bf16x8 pf = *(const bf16x8*)(pw + pbyt);
#pragma unroll
        for (int o = 0; o < 8; ++o) {
          const int vrow = o * 16 + lr;
          const int vbyt = vrow * 128 + ((kk2 * 64 + lg * 16) ^ ((vrow & 7) << 4));
          const bf16x8 vf = *(const bf16x8*)(vbase + vbyt);
          acc_o[o] = __builtin_amdgcn_mfma_f32_16x16x32_bf16(pf, vf, acc_o[o], 0, 0, 0);
        }
      }
    }

#pragma unroll
    for (int r = 0; r < 4; ++r) {
      const float inv = 1.f / l_r[r];
      const int t = qbase + w * 16 + lg * 4 + r;
#pragma unroll
      for (int o = 0; o < 8; ++o)
        ctx[(size_t)t * 4096 + h * 128 + o * 16 + lr] = f2bf(acc_o[o][r] * inv);
    }
    __syncthreads();
  }
}

// ---------------- launch -----------------------------------------------------
extern "C" void kernel_launch(void* const* d_in, const int* in_sizes, int n_in,
                              void* d_out, int out_size, void* d_ws, size_t ws_size,
                              hipStream_t stream) {
  (void)in_sizes; (void)n_in; (void)out_size; (void)ws_size;
  const float* hidden = (const float*)d_in[1];
  const float* w_qkv = (const float*)d_in[2];
  const float* w_o = (const float*)d_in[3];
  float* out = (float*)d_out;
  char* ws = (char*)d_ws;

  u16* xb    = (u16*)(ws + 0);                   // 2048*4096   bf16  (16 MB)
  u16* wqkvb = (u16*)(ws + 16777216);            // 6144*4096   bf16  (48 MB)
  u16* wob   = (u16*)(ws + 67108864);            // 4096*4096   bf16  (32 MB)
  u16* qkvb  = (u16*)(ws + 100663296);           // 2048*6144   bf16  (24 MB)
  u16* vTb   = (u16*)(ws + 125829120);           // 8*128*2048  bf16  (4 MB)
  u16* ctxb  = (u16*)(ws + 130023424);           // 2048*4096   bf16  (16 MB)

  cvt_bf16<<<4096, 256, 0, stream>>>(hidden, xb, (long)2048 * 4096);
  cvt_bf16<<<8192, 256, 0, stream>>>(w_qkv, wqkvb, (long)6144 * 4096);
  cvt_bf16<<<8192, 256, 0, stream>>>(w_o, wob, (long)4096 * 4096);
  // QKV: 256x192 tiles -> 8x32 = 256 blocks (1/CU, 100% fill)
  gemmQ<256, 192, u16><<<256, 512, 0, stream>>>(xb, wqkvb, qkvb, 2048, 6144, 4096);
  vtrans<<<dim3(32, 8), 256, 0, stream>>>(qkvb, vTb);
  attn<<<dim3(16, 32), 256, 0, stream>>>(qkvb, vTb, ctxb);
  // O-proj: 128x256 tiles -> 16x16 = 256 blocks
  gemmQ<128, 256, float><<<256, 512, 0, stream>>>(ctxb, wob, out, 2048, 4096, 4096);
}